// Round 1
// baseline (3806.594 us; speedup 1.0000x reference)
//
#include <hip/hip_runtime.h>
#include <cstdint>
#include <cstddef>

#define T_DIM 1024
#define S_DIM 1024
#define N_HEADS 32
#define D_HEAD 128

// ---------------------------------------------------------------------------
// K1: logits[n][t][s] = Q[n,t,:] . K[n,s,:]   (64x64 causal tiles, fp32)
// ---------------------------------------------------------------------------
__global__ __launch_bounds__(256) void qk_kernel(const float* __restrict__ Q,
                                                 const float* __restrict__ K,
                                                 float* __restrict__ L) {
    const int st = blockIdx.x;   // s tile
    const int tt = blockIdx.y;   // t tile
    const int n  = blockIdx.z;
    if (st > tt) return;         // causal: only s-tile <= t-tile

    __shared__ float Qst[32][68];   // [k][t_row], padded
    __shared__ float Kst[32][68];   // [k][s_row]

    const int tid = threadIdx.x;
    const int tx = tid & 15, ty = tid >> 4;

    const float* Qn = Q + ((size_t)n * T_DIM + (size_t)tt * 64) * D_HEAD;
    const float* Kn = K + ((size_t)n * S_DIM + (size_t)st * 64) * D_HEAD;

    float acc[4][4] = {};

    for (int kb = 0; kb < D_HEAD; kb += 32) {
        #pragma unroll
        for (int l = 0; l < 2; ++l) {
            int idx = tid + l * 256;           // 512 float4 loads total
            int row = idx >> 3;
            int c4  = (idx & 7) * 4;
            float4 q = *(const float4*)(Qn + (size_t)row * D_HEAD + kb + c4);
            Qst[c4 + 0][row] = q.x; Qst[c4 + 1][row] = q.y;
            Qst[c4 + 2][row] = q.z; Qst[c4 + 3][row] = q.w;
            float4 k = *(const float4*)(Kn + (size_t)row * D_HEAD + kb + c4);
            Kst[c4 + 0][row] = k.x; Kst[c4 + 1][row] = k.y;
            Kst[c4 + 2][row] = k.z; Kst[c4 + 3][row] = k.w;
        }
        __syncthreads();
        #pragma unroll
        for (int k = 0; k < 32; ++k) {
            float4 a = *(const float4*)&Qst[k][ty * 4];
            float4 b = *(const float4*)&Kst[k][tx * 4];
            acc[0][0] += a.x * b.x; acc[0][1] += a.x * b.y; acc[0][2] += a.x * b.z; acc[0][3] += a.x * b.w;
            acc[1][0] += a.y * b.x; acc[1][1] += a.y * b.y; acc[1][2] += a.y * b.z; acc[1][3] += a.y * b.w;
            acc[2][0] += a.z * b.x; acc[2][1] += a.z * b.y; acc[2][2] += a.z * b.z; acc[2][3] += a.z * b.w;
            acc[3][0] += a.w * b.x; acc[3][1] += a.w * b.y; acc[3][2] += a.w * b.z; acc[3][3] += a.w * b.w;
        }
        __syncthreads();
    }

    const int trow = tt * 64 + ty * 4;
    const int scol = st * 64 + tx * 4;
    #pragma unroll
    for (int i = 0; i < 4; ++i) {
        float4 r;
        r.x = acc[i][0]; r.y = acc[i][1]; r.z = acc[i][2]; r.w = acc[i][3];
        *(float4*)&L[((size_t)n * T_DIM + trow + i) * S_DIM + scol] = r;
    }
}

// ---------------------------------------------------------------------------
// K2/K4: cross-head projection (pointwise in (t,s), mixes the 32 heads).
// out_m = x_m*(1+qdd[t,m]+kdd[s,m]) + sum_n x_n*sw[n,m]
//       + sum_i qh_i*qw2[t,i,m] + sum_i kh_i*kw2[s,i,m]   (+ mask if pre)
// qh_i = sum_n x_n*qw1[t,i,n],  kh_i = sum_n x_n*kw1[s,i,n]
// Block: 16 t x 64 s tile; each thread handles 2 t (shares sw/kw LDS reads).
// ---------------------------------------------------------------------------
template <int ADD_MASK>
__global__ __launch_bounds__(256) void proj_kernel(float* __restrict__ L,
                                                   const float* __restrict__ sw,
                                                   const float* __restrict__ qw1,
                                                   const float* __restrict__ qw2,
                                                   const float* __restrict__ kw1,
                                                   const float* __restrict__ kw2,
                                                   const float* __restrict__ qdd,
                                                   const float* __restrict__ kdd,
                                                   const float* __restrict__ mask) {
    const int s0 = blockIdx.x * 64;
    const int t0 = blockIdx.y * 16;
    const int smaxblk = ((t0 >> 6) + 1) << 6;   // causal row extent (64-aligned)
    if (s0 >= smaxblk) return;

    __shared__ __align__(16) float sw_s[32][32];   // [n][m]
    __shared__ float kw1s[2][32][66];              // [i][n][s_rel] (conflict-free in s)
    __shared__ float kw2s[2][32][66];
    __shared__ float kdds[32][66];                 // [n][s_rel]
    __shared__ float qw1s[16][2][32];              // [t_rel][i][n] (uniform reads)
    __shared__ float qw2s[16][2][32];
    __shared__ float qdds[16][32];

    const int tid = threadIdx.x;

    #pragma unroll
    for (int l = 0; l < 4; ++l) { int e = tid + l * 256; sw_s[e >> 5][e & 31] = sw[e]; }
    #pragma unroll
    for (int l = 0; l < 16; ++l) {
        int e = tid + l * 256;                  // 4096 elems
        int srel = e >> 6, rem = e & 63;
        int i = rem >> 5, nn = rem & 31;
        kw1s[i][nn][srel] = kw1[(size_t)(s0 + srel) * 64 + rem];
        kw2s[i][nn][srel] = kw2[(size_t)(s0 + srel) * 64 + rem];
    }
    #pragma unroll
    for (int l = 0; l < 8; ++l) {
        int e = tid + l * 256;                  // 2048 elems
        int srel = e >> 5, nn = e & 31;
        kdds[nn][srel] = kdd[(size_t)(s0 + srel) * 32 + nn];
    }
    #pragma unroll
    for (int l = 0; l < 4; ++l) {
        int e = tid + l * 256;                  // 1024 elems
        int trel = e >> 6, rem = e & 63;
        qw1s[trel][rem >> 5][rem & 31] = qw1[(size_t)(t0 + trel) * 64 + rem];
        qw2s[trel][rem >> 5][rem & 31] = qw2[(size_t)(t0 + trel) * 64 + rem];
    }
    #pragma unroll
    for (int l = 0; l < 2; ++l) {
        int e = tid + l * 256;                  // 512 elems
        qdds[e >> 5][e & 31] = qdd[(size_t)(t0 + (e >> 5)) * 32 + (e & 31)];
    }
    __syncthreads();

    const int sl = tid & 63;
    const int tg = tid >> 6;
    const int s  = s0 + sl;

    #pragma unroll
    for (int tt = 0; tt < 2; ++tt) {
        const int trA = tg * 4 + tt * 2;
        const int trB = trA + 1;
        const int tA = t0 + trA, tB = t0 + trB;

        float xA[32], xB[32];
        #pragma unroll
        for (int nn = 0; nn < 32; ++nn) {
            xA[nn] = L[((size_t)nn * T_DIM + tA) * S_DIM + s];
            xB[nn] = L[((size_t)nn * T_DIM + tB) * S_DIM + s];
        }

        float qhA0 = 0, qhA1 = 0, qhB0 = 0, qhB1 = 0;
        float khA0 = 0, khA1 = 0, khB0 = 0, khB1 = 0;
        #pragma unroll
        for (int nn = 0; nn < 32; ++nn) {
            float k0 = kw1s[0][nn][sl], k1 = kw1s[1][nn][sl];
            khA0 += xA[nn] * k0; khA1 += xA[nn] * k1;
            khB0 += xB[nn] * k0; khB1 += xB[nn] * k1;
            qhA0 += xA[nn] * qw1s[trA][0][nn]; qhA1 += xA[nn] * qw1s[trA][1][nn];
            qhB0 += xB[nn] * qw1s[trB][0][nn]; qhB1 += xB[nn] * qw1s[trB][1][nn];
        }

        float oA[32], oB[32];
        #pragma unroll
        for (int m = 0; m < 32; ++m) {
            oA[m] = xA[m] * (1.0f + qdds[trA][m] + kdds[m][sl])
                  + qhA0 * qw2s[trA][0][m] + qhA1 * qw2s[trA][1][m]
                  + khA0 * kw2s[0][m][sl] + khA1 * kw2s[1][m][sl];
            oB[m] = xB[m] * (1.0f + qdds[trB][m] + kdds[m][sl])
                  + qhB0 * qw2s[trB][0][m] + qhB1 * qw2s[trB][1][m]
                  + khB0 * kw2s[0][m][sl] + khB1 * kw2s[1][m][sl];
        }

        // 32x32 head mix: share each sw row read between the two t's
        #pragma unroll
        for (int nn = 0; nn < 32; ++nn) {
            float a = xA[nn], b = xB[nn];
            const float4* row = (const float4*)sw_s[nn];
            #pragma unroll
            for (int mv = 0; mv < 8; ++mv) {
                float4 w = row[mv];
                oA[mv * 4 + 0] += a * w.x; oA[mv * 4 + 1] += a * w.y;
                oA[mv * 4 + 2] += a * w.z; oA[mv * 4 + 3] += a * w.w;
                oB[mv * 4 + 0] += b * w.x; oB[mv * 4 + 1] += b * w.y;
                oB[mv * 4 + 2] += b * w.z; oB[mv * 4 + 3] += b * w.w;
            }
        }

        float mA = 0.0f, mB = 0.0f;
        if (ADD_MASK) {
            mA = mask[(size_t)tA * S_DIM + s];
            mB = mask[(size_t)tB * S_DIM + s];
        }
        #pragma unroll
        for (int m = 0; m < 32; ++m) {
            L[((size_t)m * T_DIM + tA) * S_DIM + s] = oA[m] + mA;
            L[((size_t)m * T_DIM + tB) * S_DIM + s] = oB[m] + mB;
        }
    }
}

// ---------------------------------------------------------------------------
// K3: softmax over s in [0, smax) per (n,t) row, in place.
// ---------------------------------------------------------------------------
__global__ __launch_bounds__(256) void softmax_kernel(float* __restrict__ L) {
    const int t = blockIdx.x;
    const int n = blockIdx.y;
    const int smax = ((t >> 6) + 1) << 6;
    float* row = L + ((size_t)n * T_DIM + t) * S_DIM;
    const int tid = threadIdx.x;

    float v[4];
    #pragma unroll
    for (int j = 0; j < 4; ++j) {
        int idx = tid + j * 256;
        v[j] = (idx < smax) ? row[idx] : -INFINITY;
    }
    float m = fmaxf(fmaxf(v[0], v[1]), fmaxf(v[2], v[3]));
    #pragma unroll
    for (int off = 32; off > 0; off >>= 1) m = fmaxf(m, __shfl_xor(m, off));

    __shared__ float redm[4];
    __shared__ float reds[4];
    if ((tid & 63) == 0) redm[tid >> 6] = m;
    __syncthreads();
    m = fmaxf(fmaxf(redm[0], redm[1]), fmaxf(redm[2], redm[3]));

    float e[4];
    float ssum = 0.0f;
    #pragma unroll
    for (int j = 0; j < 4; ++j) {
        int idx = tid + j * 256;
        e[j] = (idx < smax) ? expf(v[j] - m) : 0.0f;
        ssum += e[j];
    }
    #pragma unroll
    for (int off = 32; off > 0; off >>= 1) ssum += __shfl_xor(ssum, off);
    if ((tid & 63) == 0) reds[tid >> 6] = ssum;
    __syncthreads();
    ssum = reds[0] + reds[1] + reds[2] + reds[3];
    const float inv = 1.0f / ssum;

    #pragma unroll
    for (int j = 0; j < 4; ++j) {
        int idx = tid + j * 256;
        if (idx < smax) row[idx] = e[j] * inv;
    }
}

// ---------------------------------------------------------------------------
// K5: O[n,t,:] = sum_s P[n,t,s] * V[n,s,:]   (64t x 128d tile per block)
// ---------------------------------------------------------------------------
__global__ __launch_bounds__(256) void av_kernel(const float* __restrict__ P,
                                                 const float* __restrict__ V,
                                                 float* __restrict__ O) {
    const int tt = blockIdx.x;
    const int n  = blockIdx.y;

    __shared__ float Pst[32][68];     // [s_k][t_row]
    __shared__ float Vs[32][128];     // [s_k][d]

    const int tid = threadIdx.x;
    const int r0 = (tid >> 5) * 8;    // 8 t-rows per thread
    const int c0 = (tid & 31) * 4;    // 4 d-cols per thread

    const float* Pn = P + ((size_t)n * T_DIM + (size_t)tt * 64) * S_DIM;
    const float* Vn = V + (size_t)n * S_DIM * D_HEAD;

    float acc[8][4] = {};
    const int nsteps = (tt + 1) * 2;  // s in [0, (tt+1)*64) in steps of 32

    for (int sb = 0; sb < nsteps; ++sb) {
        const int sbase = sb * 32;
        #pragma unroll
        for (int l = 0; l < 2; ++l) {
            int idx = tid + l * 256;
            int row = idx >> 3;
            int c4  = (idx & 7) * 4;
            float4 p = *(const float4*)(Pn + (size_t)row * S_DIM + sbase + c4);
            Pst[c4 + 0][row] = p.x; Pst[c4 + 1][row] = p.y;
            Pst[c4 + 2][row] = p.z; Pst[c4 + 3][row] = p.w;
        }
        #pragma unroll
        for (int l = 0; l < 4; ++l) {
            int idx = tid + l * 256;
            int sv = idx >> 5;
            int c4 = (idx & 31) * 4;
            *(float4*)&Vs[sv][c4] = *(const float4*)(Vn + (size_t)(sbase + sv) * D_HEAD + c4);
        }
        __syncthreads();
        #pragma unroll
        for (int k = 0; k < 32; ++k) {
            float4 b  = *(const float4*)&Vs[k][c0];
            float4 a0 = *(const float4*)&Pst[k][r0];
            float4 a1 = *(const float4*)&Pst[k][r0 + 4];
            acc[0][0] += a0.x * b.x; acc[0][1] += a0.x * b.y; acc[0][2] += a0.x * b.z; acc[0][3] += a0.x * b.w;
            acc[1][0] += a0.y * b.x; acc[1][1] += a0.y * b.y; acc[1][2] += a0.y * b.z; acc[1][3] += a0.y * b.w;
            acc[2][0] += a0.z * b.x; acc[2][1] += a0.z * b.y; acc[2][2] += a0.z * b.z; acc[2][3] += a0.z * b.w;
            acc[3][0] += a0.w * b.x; acc[3][1] += a0.w * b.y; acc[3][2] += a0.w * b.z; acc[3][3] += a0.w * b.w;
            acc[4][0] += a1.x * b.x; acc[4][1] += a1.x * b.y; acc[4][2] += a1.x * b.z; acc[4][3] += a1.x * b.w;
            acc[5][0] += a1.y * b.x; acc[5][1] += a1.y * b.y; acc[5][2] += a1.y * b.z; acc[5][3] += a1.y * b.w;
            acc[6][0] += a1.z * b.x; acc[6][1] += a1.z * b.y; acc[6][2] += a1.z * b.z; acc[6][3] += a1.z * b.w;
            acc[7][0] += a1.w * b.x; acc[7][1] += a1.w * b.y; acc[7][2] += a1.w * b.z; acc[7][3] += a1.w * b.w;
        }
        __syncthreads();
    }

    #pragma unroll
    for (int i = 0; i < 8; ++i) {
        float4 r;
        r.x = acc[i][0]; r.y = acc[i][1]; r.z = acc[i][2]; r.w = acc[i][3];
        *(float4*)&O[((size_t)n * T_DIM + tt * 64 + r0 + i) * D_HEAD + c0] = r;
    }
}

// ---------------------------------------------------------------------------
extern "C" void kernel_launch(void* const* d_in, const int* in_sizes, int n_in,
                              void* d_out, int out_size, void* d_ws, size_t ws_size,
                              hipStream_t stream) {
    const float* Q    = (const float*)d_in[0];
    const float* K    = (const float*)d_in[1];
    const float* V    = (const float*)d_in[2];
    const float* mask = (const float*)d_in[3];
    const float* sw_pre  = (const float*)d_in[4];
    const float* qw1_pre = (const float*)d_in[5];
    const float* qw2_pre = (const float*)d_in[6];
    const float* kw1_pre = (const float*)d_in[7];
    const float* kw2_pre = (const float*)d_in[8];
    const float* qdd_pre = (const float*)d_in[9];
    const float* kdd_pre = (const float*)d_in[10];
    const float* sw_post  = (const float*)d_in[11];
    const float* qw1_post = (const float*)d_in[12];
    const float* qw2_post = (const float*)d_in[13];
    const float* kw1_post = (const float*)d_in[14];
    const float* kw2_post = (const float*)d_in[15];
    const float* qdd_post = (const float*)d_in[16];
    const float* kdd_post = (const float*)d_in[17];

    float* L = (float*)d_ws;           // [N][T][S] fp32 = 134 MB
    float* O = (float*)d_out;          // [N][T][D] fp32

    qk_kernel<<<dim3(16, 16, 32), 256, 0, stream>>>(Q, K, L);
    proj_kernel<1><<<dim3(16, 64), 256, 0, stream>>>(L, sw_pre, qw1_pre, qw2_pre,
                                                     kw1_pre, kw2_pre, qdd_pre, kdd_pre, mask);
    softmax_kernel<<<dim3(1024, 32), 256, 0, stream>>>(L);
    proj_kernel<0><<<dim3(16, 64), 256, 0, stream>>>(L, sw_post, qw1_post, qw2_post,
                                                     kw1_post, kw2_post, qdd_post, kdd_post, nullptr);
    av_kernel<<<dim3(16, 32), 256, 0, stream>>>(L, V, O);
}

// Round 2
// 1038.664 us; speedup vs baseline: 3.6649x; 3.6649x over previous
//
#include <hip/hip_runtime.h>
#include <cstdint>
#include <cstddef>

#define T_DIM 1024
#define S_DIM 1024
#define N_HEADS 32
#define D_HEAD 128

// ---------------------------------------------------------------------------
// K1: logits[n][t][s] = Q[n,t,:] . K[n,s,:]   (64x64 causal tiles, fp32)
// ---------------------------------------------------------------------------
__global__ __launch_bounds__(256) void qk_kernel(const float* __restrict__ Q,
                                                 const float* __restrict__ K,
                                                 float* __restrict__ L) {
    const int st = blockIdx.x;   // s tile
    const int tt = blockIdx.y;   // t tile
    const int n  = blockIdx.z;
    if (st > tt) return;         // causal: only s-tile <= t-tile

    __shared__ float Qst[32][68];   // [k][t_row], padded
    __shared__ float Kst[32][68];   // [k][s_row]

    const int tid = threadIdx.x;
    const int tx = tid & 15, ty = tid >> 4;

    const float* Qn = Q + ((size_t)n * T_DIM + (size_t)tt * 64) * D_HEAD;
    const float* Kn = K + ((size_t)n * S_DIM + (size_t)st * 64) * D_HEAD;

    float acc[4][4] = {};

    for (int kb = 0; kb < D_HEAD; kb += 32) {
        #pragma unroll
        for (int l = 0; l < 2; ++l) {
            int idx = tid + l * 256;           // 512 float4 loads total
            int row = idx >> 3;
            int c4  = (idx & 7) * 4;
            float4 q = *(const float4*)(Qn + (size_t)row * D_HEAD + kb + c4);
            Qst[c4 + 0][row] = q.x; Qst[c4 + 1][row] = q.y;
            Qst[c4 + 2][row] = q.z; Qst[c4 + 3][row] = q.w;
            float4 k = *(const float4*)(Kn + (size_t)row * D_HEAD + kb + c4);
            Kst[c4 + 0][row] = k.x; Kst[c4 + 1][row] = k.y;
            Kst[c4 + 2][row] = k.z; Kst[c4 + 3][row] = k.w;
        }
        __syncthreads();
        #pragma unroll
        for (int k = 0; k < 32; ++k) {
            float4 a = *(const float4*)&Qst[k][ty * 4];
            float4 b = *(const float4*)&Kst[k][tx * 4];
            acc[0][0] += a.x * b.x; acc[0][1] += a.x * b.y; acc[0][2] += a.x * b.z; acc[0][3] += a.x * b.w;
            acc[1][0] += a.y * b.x; acc[1][1] += a.y * b.y; acc[1][2] += a.y * b.z; acc[1][3] += a.y * b.w;
            acc[2][0] += a.z * b.x; acc[2][1] += a.z * b.y; acc[2][2] += a.z * b.z; acc[2][3] += a.z * b.w;
            acc[3][0] += a.w * b.x; acc[3][1] += a.w * b.y; acc[3][2] += a.w * b.z; acc[3][3] += a.w * b.w;
        }
        __syncthreads();
    }

    const int trow = tt * 64 + ty * 4;
    const int scol = st * 64 + tx * 4;
    #pragma unroll
    for (int i = 0; i < 4; ++i) {
        float4 r;
        r.x = acc[i][0]; r.y = acc[i][1]; r.z = acc[i][2]; r.w = acc[i][3];
        *(float4*)&L[((size_t)n * T_DIM + trow + i) * S_DIM + scol] = r;
    }
}

// ---------------------------------------------------------------------------
// K2/K4: cross-head projection, one (t,s) point per thread.
// o[m] = sum_n x[n]*sw[n,m] + qh_i*qw2[t,i,m] + kh_i*kw2[s,i,m]
//        + x[m]*(1+qdd[t,m]+kdd[s,m])   (+ inline causal mask if pre)
// sw/qw1/qw2/qdd are wave-uniform -> scalar loads (SGPR operands in FMAs).
// kw1/kw2/kdd are s-dependent -> LDS, stride-1 in s (conflict-free).
// x[32]+o[32] ~ 90 VGPR -> no spills (the round-1 killer).
// ---------------------------------------------------------------------------
template <int ADD_MASK>
__global__ __launch_bounds__(256, 4) void proj_kernel(float* __restrict__ L,
                                                      const float* __restrict__ sw,
                                                      const float* __restrict__ qw1,
                                                      const float* __restrict__ qw2,
                                                      const float* __restrict__ kw1,
                                                      const float* __restrict__ kw2,
                                                      const float* __restrict__ qdd,
                                                      const float* __restrict__ kdd) {
    const int s0 = blockIdx.x * 64;
    const int t0 = blockIdx.y * 16;
    const int smaxblk = ((t0 >> 6) + 1) << 6;   // causal row extent (64-aligned)
    if (s0 >= smaxblk) return;

    __shared__ float kw1s[2][32][64];   // [i][n][s_rel]
    __shared__ float kw2s[2][32][64];   // [i][m][s_rel]
    __shared__ float kdds[32][64];      // [n][s_rel]

    const int tid = threadIdx.x;

    #pragma unroll
    for (int l = 0; l < 16; ++l) {
        int e = tid + l * 256;                  // 4096 elems each
        int srel = e >> 6, rem = e & 63;
        int i = rem >> 5, nn = rem & 31;
        kw1s[i][nn][srel] = kw1[(size_t)(s0 + srel) * 64 + rem];
        kw2s[i][nn][srel] = kw2[(size_t)(s0 + srel) * 64 + rem];
    }
    #pragma unroll
    for (int l = 0; l < 8; ++l) {
        int e = tid + l * 256;                  // 2048 elems
        int srel = e >> 5, nn = e & 31;
        kdds[nn][srel] = kdd[(size_t)(s0 + srel) * 32 + nn];
    }
    __syncthreads();

    const int sl = tid & 63;
    const int tg = tid >> 6;
    const int s  = s0 + sl;

    for (int pass = 0; pass < 4; ++pass) {
        const int tr = pass * 4 + tg;           // 0..15
        const int t  = t0 + tr;
        const float* qw1t = qw1 + (size_t)t * 64;   // uniform -> s_load
        const float* qw2t = qw2 + (size_t)t * 64;
        const float* qddt = qdd + (size_t)t * 32;

        float x[32];
        #pragma unroll
        for (int nn = 0; nn < 32; ++nn)
            x[nn] = L[((size_t)nn * T_DIM + t) * S_DIM + s];

        float o[32];
        #pragma unroll
        for (int m = 0; m < 32; ++m) o[m] = 0.0f;
        float qh0 = 0, qh1 = 0, kh0 = 0, kh1 = 0;

        #pragma unroll
        for (int nn = 0; nn < 32; ++nn) {
            const float xn = x[nn];
            qh0 += xn * qw1t[nn];               // SGPR
            qh1 += xn * qw1t[32 + nn];          // SGPR
            kh0 += xn * kw1s[0][nn][sl];        // LDS
            kh1 += xn * kw1s[1][nn][sl];        // LDS
            #pragma unroll
            for (int m = 0; m < 32; ++m)
                o[m] += xn * sw[nn * 32 + m];   // SGPR operand FMA
        }

        #pragma unroll
        for (int m = 0; m < 32; ++m) {
            float r = o[m]
                    + qh0 * qw2t[m] + qh1 * qw2t[32 + m]
                    + kh0 * kw2s[0][m][sl] + kh1 * kw2s[1][m][sl]
                    + x[m] * (1.0f + qddt[m] + kdds[m][sl]);
            if (ADD_MASK) r = (s <= t) ? r : -1.0e38f;   // inline causal mask
            L[((size_t)m * T_DIM + t) * S_DIM + s] = r;
        }
    }
}

// ---------------------------------------------------------------------------
// K3: softmax over s in [0, smax) per (n,t) row, in place.
// ---------------------------------------------------------------------------
__global__ __launch_bounds__(256) void softmax_kernel(float* __restrict__ L) {
    const int t = blockIdx.x;
    const int n = blockIdx.y;
    const int smax = ((t >> 6) + 1) << 6;
    float* row = L + ((size_t)n * T_DIM + t) * S_DIM;
    const int tid = threadIdx.x;

    float v[4];
    #pragma unroll
    for (int j = 0; j < 4; ++j) {
        int idx = tid + j * 256;
        v[j] = (idx < smax) ? row[idx] : -INFINITY;
    }
    float m = fmaxf(fmaxf(v[0], v[1]), fmaxf(v[2], v[3]));
    #pragma unroll
    for (int off = 32; off > 0; off >>= 1) m = fmaxf(m, __shfl_xor(m, off));

    __shared__ float redm[4];
    __shared__ float reds[4];
    if ((tid & 63) == 0) redm[tid >> 6] = m;
    __syncthreads();
    m = fmaxf(fmaxf(redm[0], redm[1]), fmaxf(redm[2], redm[3]));

    float e[4];
    float ssum = 0.0f;
    #pragma unroll
    for (int j = 0; j < 4; ++j) {
        int idx = tid + j * 256;
        e[j] = (idx < smax) ? expf(v[j] - m) : 0.0f;
        ssum += e[j];
    }
    #pragma unroll
    for (int off = 32; off > 0; off >>= 1) ssum += __shfl_xor(ssum, off);
    if ((tid & 63) == 0) reds[tid >> 6] = ssum;
    __syncthreads();
    ssum = reds[0] + reds[1] + reds[2] + reds[3];
    const float inv = 1.0f / ssum;

    #pragma unroll
    for (int j = 0; j < 4; ++j) {
        int idx = tid + j * 256;
        if (idx < smax) row[idx] = e[j] * inv;
    }
}

// ---------------------------------------------------------------------------
// K5: O[n,t,:] = sum_s P[n,t,s] * V[n,s,:]   (64t x 128d tile per block)
// ---------------------------------------------------------------------------
__global__ __launch_bounds__(256) void av_kernel(const float* __restrict__ P,
                                                 const float* __restrict__ V,
                                                 float* __restrict__ O) {
    const int tt = blockIdx.x;
    const int n  = blockIdx.y;

    __shared__ float Pst[32][68];     // [s_k][t_row]
    __shared__ float Vs[32][128];     // [s_k][d]

    const int tid = threadIdx.x;
    const int r0 = (tid >> 5) * 8;    // 8 t-rows per thread
    const int c0 = (tid & 31) * 4;    // 4 d-cols per thread

    const float* Pn = P + ((size_t)n * T_DIM + (size_t)tt * 64) * S_DIM;
    const float* Vn = V + (size_t)n * S_DIM * D_HEAD;

    float acc[8][4] = {};
    const int nsteps = (tt + 1) * 2;  // s in [0, (tt+1)*64) in steps of 32

    for (int sb = 0; sb < nsteps; ++sb) {
        const int sbase = sb * 32;
        #pragma unroll
        for (int l = 0; l < 2; ++l) {
            int idx = tid + l * 256;
            int row = idx >> 3;
            int c4  = (idx & 7) * 4;
            float4 p = *(const float4*)(Pn + (size_t)row * S_DIM + sbase + c4);
            Pst[c4 + 0][row] = p.x; Pst[c4 + 1][row] = p.y;
            Pst[c4 + 2][row] = p.z; Pst[c4 + 3][row] = p.w;
        }
        #pragma unroll
        for (int l = 0; l < 4; ++l) {
            int idx = tid + l * 256;
            int sv = idx >> 5;
            int c4 = (idx & 31) * 4;
            *(float4*)&Vs[sv][c4] = *(const float4*)(Vn + (size_t)(sbase + sv) * D_HEAD + c4);
        }
        __syncthreads();
        #pragma unroll
        for (int k = 0; k < 32; ++k) {
            float4 b  = *(const float4*)&Vs[k][c0];
            float4 a0 = *(const float4*)&Pst[k][r0];
            float4 a1 = *(const float4*)&Pst[k][r0 + 4];
            acc[0][0] += a0.x * b.x; acc[0][1] += a0.x * b.y; acc[0][2] += a0.x * b.z; acc[0][3] += a0.x * b.w;
            acc[1][0] += a0.y * b.x; acc[1][1] += a0.y * b.y; acc[1][2] += a0.y * b.z; acc[1][3] += a0.y * b.w;
            acc[2][0] += a0.z * b.x; acc[2][1] += a0.z * b.y; acc[2][2] += a0.z * b.z; acc[2][3] += a0.z * b.w;
            acc[3][0] += a0.w * b.x; acc[3][1] += a0.w * b.y; acc[3][2] += a0.w * b.z; acc[3][3] += a0.w * b.w;
            acc[4][0] += a1.x * b.x; acc[4][1] += a1.x * b.y; acc[4][2] += a1.x * b.z; acc[4][3] += a1.x * b.w;
            acc[5][0] += a1.y * b.x; acc[5][1] += a1.y * b.y; acc[5][2] += a1.y * b.z; acc[5][3] += a1.y * b.w;
            acc[6][0] += a1.z * b.x; acc[6][1] += a1.z * b.y; acc[6][2] += a1.z * b.z; acc[6][3] += a1.z * b.w;
            acc[7][0] += a1.w * b.x; acc[7][1] += a1.w * b.y; acc[7][2] += a1.w * b.z; acc[7][3] += a1.w * b.w;
        }
        __syncthreads();
    }

    #pragma unroll
    for (int i = 0; i < 8; ++i) {
        float4 r;
        r.x = acc[i][0]; r.y = acc[i][1]; r.z = acc[i][2]; r.w = acc[i][3];
        *(float4*)&O[((size_t)n * T_DIM + tt * 64 + r0 + i) * D_HEAD + c0] = r;
    }
}

// ---------------------------------------------------------------------------
extern "C" void kernel_launch(void* const* d_in, const int* in_sizes, int n_in,
                              void* d_out, int out_size, void* d_ws, size_t ws_size,
                              hipStream_t stream) {
    const float* Q    = (const float*)d_in[0];
    const float* K    = (const float*)d_in[1];
    const float* V    = (const float*)d_in[2];
    const float* sw_pre  = (const float*)d_in[4];
    const float* qw1_pre = (const float*)d_in[5];
    const float* qw2_pre = (const float*)d_in[6];
    const float* kw1_pre = (const float*)d_in[7];
    const float* kw2_pre = (const float*)d_in[8];
    const float* qdd_pre = (const float*)d_in[9];
    const float* kdd_pre = (const float*)d_in[10];
    const float* sw_post  = (const float*)d_in[11];
    const float* qw1_post = (const float*)d_in[12];
    const float* qw2_post = (const float*)d_in[13];
    const float* kw1_post = (const float*)d_in[14];
    const float* kw2_post = (const float*)d_in[15];
    const float* qdd_post = (const float*)d_in[16];
    const float* kdd_post = (const float*)d_in[17];

    float* L = (float*)d_ws;           // [N][T][S] fp32 = 134 MB
    float* O = (float*)d_out;          // [N][T][D] fp32

    qk_kernel<<<dim3(16, 16, 32), 256, 0, stream>>>(Q, K, L);
    proj_kernel<1><<<dim3(16, 64), 256, 0, stream>>>(L, sw_pre, qw1_pre, qw2_pre,
                                                     kw1_pre, kw2_pre, qdd_pre, kdd_pre);
    softmax_kernel<<<dim3(1024, 32), 256, 0, stream>>>(L);
    proj_kernel<0><<<dim3(16, 64), 256, 0, stream>>>(L, sw_post, qw1_post, qw2_post,
                                                     kw1_post, kw2_post, qdd_post, kdd_post);
    av_kernel<<<dim3(16, 32), 256, 0, stream>>>(L, V, O);
}

// Round 3
// 462.421 us; speedup vs baseline: 8.2319x; 2.2461x over previous
//
#include <hip/hip_runtime.h>
#include <hip/hip_bf16.h>
#include <cstdint>
#include <cstddef>

#define T_DIM 1024
#define S_DIM 1024
#define N_HEADS 32
#define D_HEAD 128

typedef __attribute__((ext_vector_type(8))) short short8;
typedef __attribute__((ext_vector_type(4))) float floatx4;

__device__ inline int pack_bf16(float a, float b) {
    __hip_bfloat162 h = __float22bfloat162_rn(make_float2(a, b));
    int r; __builtin_memcpy(&r, &h, 4); return r;
}

// ---------------------------------------------------------------------------
// K1: logits[n][t][s] = Q[n,t,:] . K[n,s,:]   (64x64 causal tiles, fp32)
// ---------------------------------------------------------------------------
__global__ __launch_bounds__(256) void qk_kernel(const float* __restrict__ Q,
                                                 const float* __restrict__ K,
                                                 float* __restrict__ L) {
    const int st = blockIdx.x;
    const int tt = blockIdx.y;
    const int n  = blockIdx.z;
    if (st > tt) return;

    __shared__ float Qst[32][68];
    __shared__ float Kst[32][68];

    const int tid = threadIdx.x;
    const int tx = tid & 15, ty = tid >> 4;

    const float* Qn = Q + ((size_t)n * T_DIM + (size_t)tt * 64) * D_HEAD;
    const float* Kn = K + ((size_t)n * S_DIM + (size_t)st * 64) * D_HEAD;

    float acc[4][4] = {};

    for (int kb = 0; kb < D_HEAD; kb += 32) {
        #pragma unroll
        for (int l = 0; l < 2; ++l) {
            int idx = tid + l * 256;
            int row = idx >> 3;
            int c4  = (idx & 7) * 4;
            float4 q = *(const float4*)(Qn + (size_t)row * D_HEAD + kb + c4);
            Qst[c4 + 0][row] = q.x; Qst[c4 + 1][row] = q.y;
            Qst[c4 + 2][row] = q.z; Qst[c4 + 3][row] = q.w;
            float4 k = *(const float4*)(Kn + (size_t)row * D_HEAD + kb + c4);
            Kst[c4 + 0][row] = k.x; Kst[c4 + 1][row] = k.y;
            Kst[c4 + 2][row] = k.z; Kst[c4 + 3][row] = k.w;
        }
        __syncthreads();
        #pragma unroll
        for (int k = 0; k < 32; ++k) {
            float4 a = *(const float4*)&Qst[k][ty * 4];
            float4 b = *(const float4*)&Kst[k][tx * 4];
            acc[0][0] += a.x * b.x; acc[0][1] += a.x * b.y; acc[0][2] += a.x * b.z; acc[0][3] += a.x * b.w;
            acc[1][0] += a.y * b.x; acc[1][1] += a.y * b.y; acc[1][2] += a.y * b.z; acc[1][3] += a.y * b.w;
            acc[2][0] += a.z * b.x; acc[2][1] += a.z * b.y; acc[2][2] += a.z * b.z; acc[2][3] += a.z * b.w;
            acc[3][0] += a.w * b.x; acc[3][1] += a.w * b.y; acc[3][2] += a.w * b.z; acc[3][3] += a.w * b.w;
        }
        __syncthreads();
    }

    const int trow = tt * 64 + ty * 4;
    const int scol = st * 64 + tx * 4;
    #pragma unroll
    for (int i = 0; i < 4; ++i) {
        float4 r;
        r.x = acc[i][0]; r.y = acc[i][1]; r.z = acc[i][2]; r.w = acc[i][3];
        *(float4*)&L[((size_t)n * T_DIM + trow + i) * S_DIM + scol] = r;
    }
}

// ---------------------------------------------------------------------------
// Precompute per-position 32x32 mixing matrices (bf16, layout [pos][m][n]):
//   out[pos][m][n] = (sw ? sw[n,m] : 0) + w1[pos,0,n]*w2[pos,0,m]
//                  + w1[pos,1,n]*w2[pos,1,m] + (n==m)*(idadd + dd[pos,m])
// ---------------------------------------------------------------------------
__global__ __launch_bounds__(256) void mat_kernel(const float* __restrict__ sw,
                                                  const float* __restrict__ w1,
                                                  const float* __restrict__ w2,
                                                  const float* __restrict__ dd,
                                                  float idadd,
                                                  ushort* __restrict__ out) {
    const int t = blockIdx.x;
    const int tid = threadIdx.x;
    const int m = tid >> 3;
    const int n0 = (tid & 7) * 4;

    const float w2m0 = w2[t * 64 + m];
    const float w2m1 = w2[t * 64 + 32 + m];
    const float ddm  = dd[t * 32 + m];

    float v[4];
    #pragma unroll
    for (int j = 0; j < 4; ++j) {
        int n = n0 + j;
        float r = w1[t * 64 + n] * w2m0 + w1[t * 64 + 32 + n] * w2m1;
        if (sw) r += sw[n * 32 + m];
        if (n == m) r += idadd + ddm;
        v[j] = r;
    }
    int p0 = pack_bf16(v[0], v[1]);
    int p1 = pack_bf16(v[2], v[3]);
    int2 st = make_int2(p0, p1);
    *(int2*)&out[(size_t)t * 1024 + m * 32 + n0] = st;
}

// ---------------------------------------------------------------------------
// Fused cross-head projection via MFMA, in place on L ([n][t][s] fp32).
// Tile: 32 t x 16 s. out[m,t,s] = sum_n (C_t[n,m] + K_s[n,m]) x[n,t,s].
//  Phase 0: gather x tile, bf16-pack into tileA ([t][s][np]) and tileB ([s][t][np]).
//  Phase 1: per-s MFMAs  D_K[m, t] = K_s^T-as-A  x-as-B   (kept in regs)
//  Phase 2/3 per m-half: stage D_K -> ldsD[t][s][m], then per-t MFMAs
//           D_C[s, m] = x-as-A  C_t-as-B, add ldsD, zero s>t, float4 store.
// ---------------------------------------------------------------------------
__global__ __launch_bounds__(256, 2) void proj_mfma(float* __restrict__ L,
                                                    const ushort* __restrict__ Cmat,
                                                    const ushort* __restrict__ Kmat) {
    const int s0 = blockIdx.x * 16;
    const int t0 = blockIdx.y * 32;
    if (s0 > t0 + 31) return;          // tile fully above diagonal

    // tileA: [t32][s16][np16] = 8192 dw.  region2 = union(tileB [s16][t32][np16]
    // (s-stride 516), ldsD [t32][s16][m16+4] (t-stride 324, s-stride 20)) = 10368 dw.
    __shared__ __align__(16) int lds[8192 + 10368];
    int* tileA = lds;
    int* tileB = lds + 8192;
    int* ldsD  = lds + 8192;

    const int tid = threadIdx.x;
    const int wv = tid >> 6, ln = tid & 63;

    // ---- Phase 0: gather + pack -------------------------------------------
    #pragma unroll
    for (int rep = 0; rep < 2; ++rep) {
        int p  = tid + rep * 256;
        int tl = p >> 4, sl = p & 15;
        const float* xp = L + (size_t)(t0 + tl) * S_DIM + (s0 + sl);
        int packed[16];
        #pragma unroll
        for (int h = 0; h < 16; ++h) {
            float a = xp[(size_t)(2 * h)     * (T_DIM * S_DIM)];
            float b = xp[(size_t)(2 * h + 1) * (T_DIM * S_DIM)];
            packed[h] = pack_bf16(a, b);
        }
        const int baseA = (tl * 16 + sl) * 16, swA = 4 * (sl & 3);
        const int baseB = sl * 516 + tl * 16,  swB = 4 * (tl & 3);
        #pragma unroll
        for (int h = 0; h < 16; ++h) {
            tileA[baseA + (h ^ swA)] = packed[h];
            tileB[baseB + (h ^ swB)] = packed[h];
        }
    }
    __syncthreads();

    const int frow = ln & 15;     // A-row / B-col / D-col lane index
    const int fkg  = ln >> 4;     // k-group (8 k each)

    // ---- Phase 1: K-side MFMAs (per s), results in regs -------------------
    floatx4 dk[4][2][2];          // [s in quarter][mh][tc]
    #pragma unroll
    for (int si = 0; si < 4; ++si) {
        const int s_l = wv * 4 + si;
        const int s_g = s0 + s_l;
        #pragma unroll
        for (int mh = 0; mh < 2; ++mh) {
            // A = K_s^T : A[m][k=n] = Kmat[s][m][n]
            const short8 af = *(const short8*)(Kmat + (size_t)s_g * 1024 + (mh * 16 + frow) * 32 + fkg * 8);
            #pragma unroll
            for (int tc = 0; tc < 2; ++tc) {
                const int* bp = &tileB[s_l * 516 + (tc * 16 + frow) * 16 + ((4 * fkg) ^ (4 * (frow & 3)))];
                const short8 bf = *(const short8*)bp;
                floatx4 z = {0.f, 0.f, 0.f, 0.f};
                dk[si][mh][tc] = __builtin_amdgcn_mfma_f32_16x16x32_bf16(af, bf, z, 0, 0, 0);
            }
        }
    }
    __syncthreads();   // tileB dead; ldsD may overwrite

    // ---- Phase 2/3: per m-half: stage D_K, C-side MFMAs, store ------------
    #pragma unroll
    for (int mh = 0; mh < 2; ++mh) {
        #pragma unroll
        for (int si = 0; si < 4; ++si) {
            const int s_l = wv * 4 + si;
            #pragma unroll
            for (int tc = 0; tc < 2; ++tc) {
                const int tl = tc * 16 + frow;          // D_K col = t
                const int off = tl * 324 + s_l * 20 + fkg * 4;  // rows m-local = fkg*4+r
                *(floatx4*)&ldsD[off] = dk[si][mh][tc];
            }
        }
        __syncthreads();

        #pragma unroll
        for (int ti = 0; ti < 8; ++ti) {
            const int tl = wv * 8 + ti;
            const int tg = t0 + tl;
            const short8 af = *(const short8*)&tileA[(tl * 16 + frow) * 16 + ((4 * fkg) ^ (4 * (frow & 3)))];
            const short8 bf = *(const short8*)(Cmat + (size_t)tg * 1024 + (mh * 16 + frow) * 32 + fkg * 8);
            floatx4 z = {0.f, 0.f, 0.f, 0.f};
            floatx4 d = __builtin_amdgcn_mfma_f32_16x16x32_bf16(af, bf, z, 0, 0, 0);

            const int m_l = frow;            // D col = m
            const int s_base = fkg * 4;      // D rows = s
            float v[4];
            #pragma unroll
            for (int r = 0; r < 4; ++r) {
                float kadd = ((const float*)ldsD)[tl * 324 + (s_base + r) * 20 + m_l];
                float val = d[r] + kadd;
                v[r] = (s0 + s_base + r > tg) ? 0.0f : val;   // zero above diagonal
            }
            float4 st; st.x = v[0]; st.y = v[1]; st.z = v[2]; st.w = v[3];
            *(float4*)&L[((size_t)(mh * 16 + m_l) * T_DIM + tg) * S_DIM + s0 + s_base] = st;
        }
        __syncthreads();
    }
}

// ---------------------------------------------------------------------------
// K3: softmax over s in [0, t] per (n,t) row, in place (exact causal bound).
// ---------------------------------------------------------------------------
__global__ __launch_bounds__(256) void softmax_kernel(float* __restrict__ L) {
    const int t = blockIdx.x;
    const int n = blockIdx.y;
    float* row = L + ((size_t)n * T_DIM + t) * S_DIM;
    const int tid = threadIdx.x;

    float v[4];
    #pragma unroll
    for (int j = 0; j < 4; ++j) {
        int idx = tid + j * 256;
        v[j] = (idx <= t) ? row[idx] : -INFINITY;
    }
    float m = fmaxf(fmaxf(v[0], v[1]), fmaxf(v[2], v[3]));
    #pragma unroll
    for (int off = 32; off > 0; off >>= 1) m = fmaxf(m, __shfl_xor(m, off));

    __shared__ float redm[4];
    __shared__ float reds[4];
    if ((tid & 63) == 0) redm[tid >> 6] = m;
    __syncthreads();
    m = fmaxf(fmaxf(redm[0], redm[1]), fmaxf(redm[2], redm[3]));

    float e[4];
    float ssum = 0.0f;
    #pragma unroll
    for (int j = 0; j < 4; ++j) {
        int idx = tid + j * 256;
        e[j] = (idx <= t) ? expf(v[j] - m) : 0.0f;
        ssum += e[j];
    }
    #pragma unroll
    for (int off = 32; off > 0; off >>= 1) ssum += __shfl_xor(ssum, off);
    if ((tid & 63) == 0) reds[tid >> 6] = ssum;
    __syncthreads();
    ssum = reds[0] + reds[1] + reds[2] + reds[3];
    const float inv = 1.0f / ssum;

    #pragma unroll
    for (int j = 0; j < 4; ++j) {
        int idx = tid + j * 256;
        if (idx <= t) row[idx] = e[j] * inv;
    }
}

// ---------------------------------------------------------------------------
// K5: O[n,t,:] = sum_s P[n,t,s] * V[n,s,:]  (64t x 128d per block, causal mask
// applied on load for the diagonal block since proj tiles are 16-granular)
// ---------------------------------------------------------------------------
__global__ __launch_bounds__(256) void av_kernel(const float* __restrict__ P,
                                                 const float* __restrict__ V,
                                                 float* __restrict__ O) {
    const int tt = blockIdx.x;
    const int n  = blockIdx.y;

    __shared__ float Pst[32][68];
    __shared__ float Vs[32][128];

    const int tid = threadIdx.x;
    const int r0 = (tid >> 5) * 8;
    const int c0 = (tid & 31) * 4;

    const float* Pn = P + ((size_t)n * T_DIM + (size_t)tt * 64) * S_DIM;
    const float* Vn = V + (size_t)n * S_DIM * D_HEAD;

    float acc[8][4] = {};
    const int nsteps = (tt + 1) * 2;

    for (int sb = 0; sb < nsteps; ++sb) {
        const int sbase = sb * 32;
        #pragma unroll
        for (int l = 0; l < 2; ++l) {
            int idx = tid + l * 256;
            int row = idx >> 3;
            int c4  = (idx & 7) * 4;
            float4 p = *(const float4*)(Pn + (size_t)row * S_DIM + sbase + c4);
            int tg = tt * 64 + row;
            int sg = sbase + c4;
            p.x = (sg + 0 <= tg) ? p.x : 0.0f;
            p.y = (sg + 1 <= tg) ? p.y : 0.0f;
            p.z = (sg + 2 <= tg) ? p.z : 0.0f;
            p.w = (sg + 3 <= tg) ? p.w : 0.0f;
            Pst[c4 + 0][row] = p.x; Pst[c4 + 1][row] = p.y;
            Pst[c4 + 2][row] = p.z; Pst[c4 + 3][row] = p.w;
        }
        #pragma unroll
        for (int l = 0; l < 4; ++l) {
            int idx = tid + l * 256;
            int sv = idx >> 5;
            int c4 = (idx & 31) * 4;
            *(float4*)&Vs[sv][c4] = *(const float4*)(Vn + (size_t)(sbase + sv) * D_HEAD + c4);
        }
        __syncthreads();
        #pragma unroll
        for (int k = 0; k < 32; ++k) {
            float4 b  = *(const float4*)&Vs[k][c0];
            float4 a0 = *(const float4*)&Pst[k][r0];
            float4 a1 = *(const float4*)&Pst[k][r0 + 4];
            acc[0][0] += a0.x * b.x; acc[0][1] += a0.x * b.y; acc[0][2] += a0.x * b.z; acc[0][3] += a0.x * b.w;
            acc[1][0] += a0.y * b.x; acc[1][1] += a0.y * b.y; acc[1][2] += a0.y * b.z; acc[1][3] += a0.y * b.w;
            acc[2][0] += a0.z * b.x; acc[2][1] += a0.z * b.y; acc[2][2] += a0.z * b.z; acc[2][3] += a0.z * b.w;
            acc[3][0] += a0.w * b.x; acc[3][1] += a0.w * b.y; acc[3][2] += a0.w * b.z; acc[3][3] += a0.w * b.w;
            acc[4][0] += a1.x * b.x; acc[4][1] += a1.x * b.y; acc[4][2] += a1.x * b.z; acc[4][3] += a1.x * b.w;
            acc[5][0] += a1.y * b.x; acc[5][1] += a1.y * b.y; acc[5][2] += a1.y * b.z; acc[5][3] += a1.y * b.w;
            acc[6][0] += a1.z * b.x; acc[6][1] += a1.z * b.y; acc[6][2] += a1.z * b.z; acc[6][3] += a1.z * b.w;
            acc[7][0] += a1.w * b.x; acc[7][1] += a1.w * b.y; acc[7][2] += a1.w * b.z; acc[7][3] += a1.w * b.w;
        }
        __syncthreads();
    }

    #pragma unroll
    for (int i = 0; i < 8; ++i) {
        float4 r;
        r.x = acc[i][0]; r.y = acc[i][1]; r.z = acc[i][2]; r.w = acc[i][3];
        *(float4*)&O[((size_t)n * T_DIM + tt * 64 + r0 + i) * D_HEAD + c0] = r;
    }
}

// ---------------------------------------------------------------------------
extern "C" void kernel_launch(void* const* d_in, const int* in_sizes, int n_in,
                              void* d_out, int out_size, void* d_ws, size_t ws_size,
                              hipStream_t stream) {
    const float* Q    = (const float*)d_in[0];
    const float* K    = (const float*)d_in[1];
    const float* V    = (const float*)d_in[2];
    const float* sw_pre  = (const float*)d_in[4];
    const float* qw1_pre = (const float*)d_in[5];
    const float* qw2_pre = (const float*)d_in[6];
    const float* kw1_pre = (const float*)d_in[7];
    const float* kw2_pre = (const float*)d_in[8];
    const float* qdd_pre = (const float*)d_in[9];
    const float* kdd_pre = (const float*)d_in[10];
    const float* sw_post  = (const float*)d_in[11];
    const float* qw1_post = (const float*)d_in[12];
    const float* qw2_post = (const float*)d_in[13];
    const float* kw1_post = (const float*)d_in[14];
    const float* kw2_post = (const float*)d_in[15];
    const float* qdd_post = (const float*)d_in[16];
    const float* kdd_post = (const float*)d_in[17];

    float* L = (float*)d_ws;          // [N][T][S] fp32, 134 MB
    float* O = (float*)d_out;

    // Mixing matrices live in d_out's tail (bf16); consumed before av writes.
    ushort* mats  = (ushort*)d_out;
    ushort* Cpre  = mats + 0 * 1024 * 1024;
    ushort* Kpre  = mats + 1 * 1024 * 1024;
    ushort* Cpost = mats + 2 * 1024 * 1024;
    ushort* Kpost = mats + 3 * 1024 * 1024;

    mat_kernel<<<1024, 256, 0, stream>>>(sw_pre,  qw1_pre,  qw2_pre,  qdd_pre,  1.0f, Cpre);
    mat_kernel<<<1024, 256, 0, stream>>>(nullptr, kw1_pre,  kw2_pre,  kdd_pre,  0.0f, Kpre);
    mat_kernel<<<1024, 256, 0, stream>>>(sw_post, qw1_post, qw2_post, qdd_post, 1.0f, Cpost);
    mat_kernel<<<1024, 256, 0, stream>>>(nullptr, kw1_post, kw2_post, kdd_post, 0.0f, Kpost);

    qk_kernel<<<dim3(16, 16, 32), 256, 0, stream>>>(Q, K, L);
    proj_mfma<<<dim3(64, 32), 256, 0, stream>>>(L, Cpre, Kpre);
    softmax_kernel<<<dim3(1024, 32), 256, 0, stream>>>(L);
    proj_mfma<<<dim3(64, 32), 256, 0, stream>>>(L, Cpost, Kpost);
    av_kernel<<<dim3(16, 32), 256, 0, stream>>>(L, V, O);
}

// Round 4
// 349.096 us; speedup vs baseline: 10.9041x; 1.3246x over previous
//
#include <hip/hip_runtime.h>
#include <hip/hip_bf16.h>
#include <cstdint>
#include <cstddef>

#define T_DIM 1024
#define S_DIM 1024
#define N_HEADS 32
#define D_HEAD 128

typedef __attribute__((ext_vector_type(8))) short short8;
typedef __attribute__((ext_vector_type(4))) float floatx4;

__device__ inline int pack_bf16(float a, float b) {
    __hip_bfloat162 h = __float22bfloat162_rn(make_float2(a, b));
    int r; __builtin_memcpy(&r, &h, 4); return r;
}

// ---------------------------------------------------------------------------
// K1: logits[n][t][s] = Q[n,t,:] . K[n,s,:]  via bf16 MFMA, 64x64 causal tiles.
// Stage Q/K tiles fp32->bf16 in LDS ([row][64 ints], 4 kb-windows of 16 ints,
// XOR swizzle 4*(row&3) inside each window). A[m=t][k=d], B[k=d][n=s].
// ---------------------------------------------------------------------------
__global__ __launch_bounds__(256, 2) void qk_mfma(const float* __restrict__ Q,
                                                  const float* __restrict__ K,
                                                  float* __restrict__ L) {
    const int st = blockIdx.x;
    const int tt = blockIdx.y;
    const int n  = blockIdx.z;
    if (st > tt) return;

    __shared__ int Qt[64 * 64];
    __shared__ int Kt[64 * 64];

    const int tid = threadIdx.x;
    const int wv = tid >> 6, ln = tid & 63;
    const int frow = ln & 15, quad = ln >> 4;

    const float* Qn = Q + ((size_t)n * T_DIM + (size_t)tt * 64) * D_HEAD;
    const float* Kn = K + ((size_t)n * S_DIM + (size_t)st * 64) * D_HEAD;

    #pragma unroll
    for (int rep = 0; rep < 8; ++rep) {
        int idx = tid + rep * 256;           // 2048 float4-tasks per tensor
        int row = idx >> 5;                  // 0..63
        int c4  = (idx & 31) * 4;            // 0..124
        int p   = c4 >> 1;                   // d-pair index (even)
        int kb  = p >> 4, w = p & 15;
        int swz = 4 * (row & 3);
        float4 q = *(const float4*)(Qn + (size_t)row * D_HEAD + c4);
        int2 qv; qv.x = pack_bf16(q.x, q.y); qv.y = pack_bf16(q.z, q.w);
        *(int2*)&Qt[row * 64 + kb * 16 + (w ^ swz)] = qv;
        float4 k = *(const float4*)(Kn + (size_t)row * D_HEAD + c4);
        int2 kv; kv.x = pack_bf16(k.x, k.y); kv.y = pack_bf16(k.z, k.w);
        *(int2*)&Kt[row * 64 + kb * 16 + (w ^ swz)] = kv;
    }
    __syncthreads();

    const int swz = 4 * (frow & 3);
    floatx4 acc[4] = {};
    #pragma unroll
    for (int kb = 0; kb < 4; ++kb) {
        const short8 af = *(const short8*)&Qt[(wv * 16 + frow) * 64 + kb * 16 + ((quad * 4) ^ swz)];
        #pragma unroll
        for (int si = 0; si < 4; ++si) {
            const short8 bf = *(const short8*)&Kt[(si * 16 + frow) * 64 + kb * 16 + ((quad * 4) ^ swz)];
            acc[si] = __builtin_amdgcn_mfma_f32_16x16x32_bf16(af, bf, acc[si], 0, 0, 0);
        }
    }

    const int tbase = tt * 64 + wv * 16 + quad * 4;
    #pragma unroll
    for (int si = 0; si < 4; ++si) {
        const int s = st * 64 + si * 16 + frow;
        #pragma unroll
        for (int r = 0; r < 4; ++r)
            L[((size_t)n * T_DIM + tbase + r) * S_DIM + s] = acc[si][r];
    }
}

// ---------------------------------------------------------------------------
// Precompute per-position 32x32 mixing matrices (bf16, layout [pos][m][n])
// ---------------------------------------------------------------------------
__global__ __launch_bounds__(256) void mat_kernel(const float* __restrict__ sw,
                                                  const float* __restrict__ w1,
                                                  const float* __restrict__ w2,
                                                  const float* __restrict__ dd,
                                                  float idadd,
                                                  ushort* __restrict__ out) {
    const int t = blockIdx.x;
    const int tid = threadIdx.x;
    const int m = tid >> 3;
    const int n0 = (tid & 7) * 4;

    const float w2m0 = w2[t * 64 + m];
    const float w2m1 = w2[t * 64 + 32 + m];
    const float ddm  = dd[t * 32 + m];

    float v[4];
    #pragma unroll
    for (int j = 0; j < 4; ++j) {
        int n = n0 + j;
        float r = w1[t * 64 + n] * w2m0 + w1[t * 64 + 32 + n] * w2m1;
        if (sw) r += sw[n * 32 + m];
        if (n == m) r += idadd + ddm;
        v[j] = r;
    }
    int p0 = pack_bf16(v[0], v[1]);
    int p1 = pack_bf16(v[2], v[3]);
    int2 st = make_int2(p0, p1);
    *(int2*)&out[(size_t)t * 1024 + m * 32 + n0] = st;
}

// ---------------------------------------------------------------------------
// Fused cross-head projection via MFMA, in place on L (unchanged from r3).
// ---------------------------------------------------------------------------
__global__ __launch_bounds__(256, 2) void proj_mfma(float* __restrict__ L,
                                                    const ushort* __restrict__ Cmat,
                                                    const ushort* __restrict__ Kmat) {
    const int s0 = blockIdx.x * 16;
    const int t0 = blockIdx.y * 32;
    if (s0 > t0 + 31) return;

    __shared__ __align__(16) int lds[8192 + 10368];
    int* tileA = lds;
    int* tileB = lds + 8192;
    int* ldsD  = lds + 8192;

    const int tid = threadIdx.x;
    const int wv = tid >> 6, ln = tid & 63;

    #pragma unroll
    for (int rep = 0; rep < 2; ++rep) {
        int p  = tid + rep * 256;
        int tl = p >> 4, sl = p & 15;
        const float* xp = L + (size_t)(t0 + tl) * S_DIM + (s0 + sl);
        int packed[16];
        #pragma unroll
        for (int h = 0; h < 16; ++h) {
            float a = xp[(size_t)(2 * h)     * (T_DIM * S_DIM)];
            float b = xp[(size_t)(2 * h + 1) * (T_DIM * S_DIM)];
            packed[h] = pack_bf16(a, b);
        }
        const int baseA = (tl * 16 + sl) * 16, swA = 4 * (sl & 3);
        const int baseB = sl * 516 + tl * 16,  swB = 4 * (tl & 3);
        #pragma unroll
        for (int h = 0; h < 16; ++h) {
            tileA[baseA + (h ^ swA)] = packed[h];
            tileB[baseB + (h ^ swB)] = packed[h];
        }
    }
    __syncthreads();

    const int frow = ln & 15;
    const int fkg  = ln >> 4;

    floatx4 dk[4][2][2];
    #pragma unroll
    for (int si = 0; si < 4; ++si) {
        const int s_l = wv * 4 + si;
        const int s_g = s0 + s_l;
        #pragma unroll
        for (int mh = 0; mh < 2; ++mh) {
            const short8 af = *(const short8*)(Kmat + (size_t)s_g * 1024 + (mh * 16 + frow) * 32 + fkg * 8);
            #pragma unroll
            for (int tc = 0; tc < 2; ++tc) {
                const int* bp = &tileB[s_l * 516 + (tc * 16 + frow) * 16 + ((4 * fkg) ^ (4 * (frow & 3)))];
                const short8 bf = *(const short8*)bp;
                floatx4 z = {0.f, 0.f, 0.f, 0.f};
                dk[si][mh][tc] = __builtin_amdgcn_mfma_f32_16x16x32_bf16(af, bf, z, 0, 0, 0);
            }
        }
    }
    __syncthreads();

    #pragma unroll
    for (int mh = 0; mh < 2; ++mh) {
        #pragma unroll
        for (int si = 0; si < 4; ++si) {
            const int s_l = wv * 4 + si;
            #pragma unroll
            for (int tc = 0; tc < 2; ++tc) {
                const int tl = tc * 16 + frow;
                const int off = tl * 324 + s_l * 20 + fkg * 4;
                *(floatx4*)&ldsD[off] = dk[si][mh][tc];
            }
        }
        __syncthreads();

        #pragma unroll
        for (int ti = 0; ti < 8; ++ti) {
            const int tl = wv * 8 + ti;
            const int tg = t0 + tl;
            const short8 af = *(const short8*)&tileA[(tl * 16 + frow) * 16 + ((4 * fkg) ^ (4 * (frow & 3)))];
            const short8 bf = *(const short8*)(Cmat + (size_t)tg * 1024 + (mh * 16 + frow) * 32 + fkg * 8);
            floatx4 z = {0.f, 0.f, 0.f, 0.f};
            floatx4 d = __builtin_amdgcn_mfma_f32_16x16x32_bf16(af, bf, z, 0, 0, 0);

            const int m_l = frow;
            const int s_base = fkg * 4;
            float v[4];
            #pragma unroll
            for (int r = 0; r < 4; ++r) {
                float kadd = ((const float*)ldsD)[tl * 324 + (s_base + r) * 20 + m_l];
                float val = d[r] + kadd;
                v[r] = (s0 + s_base + r > tg) ? 0.0f : val;
            }
            float4 st; st.x = v[0]; st.y = v[1]; st.z = v[2]; st.w = v[3];
            *(float4*)&L[((size_t)(mh * 16 + m_l) * T_DIM + tg) * S_DIM + s0 + s_base] = st;
        }
        __syncthreads();
    }
}

// ---------------------------------------------------------------------------
// K3: softmax over s in [0, t] per (n,t) row, in place.
// ---------------------------------------------------------------------------
__global__ __launch_bounds__(256) void softmax_kernel(float* __restrict__ L) {
    const int t = blockIdx.x;
    const int n = blockIdx.y;
    float* row = L + ((size_t)n * T_DIM + t) * S_DIM;
    const int tid = threadIdx.x;

    float v[4];
    #pragma unroll
    for (int j = 0; j < 4; ++j) {
        int idx = tid + j * 256;
        v[j] = (idx <= t) ? row[idx] : -INFINITY;
    }
    float m = fmaxf(fmaxf(v[0], v[1]), fmaxf(v[2], v[3]));
    #pragma unroll
    for (int off = 32; off > 0; off >>= 1) m = fmaxf(m, __shfl_xor(m, off));

    __shared__ float redm[4];
    __shared__ float reds[4];
    if ((tid & 63) == 0) redm[tid >> 6] = m;
    __syncthreads();
    m = fmaxf(fmaxf(redm[0], redm[1]), fmaxf(redm[2], redm[3]));

    float e[4];
    float ssum = 0.0f;
    #pragma unroll
    for (int j = 0; j < 4; ++j) {
        int idx = tid + j * 256;
        e[j] = (idx <= t) ? expf(v[j] - m) : 0.0f;
        ssum += e[j];
    }
    #pragma unroll
    for (int off = 32; off > 0; off >>= 1) ssum += __shfl_xor(ssum, off);
    if ((tid & 63) == 0) reds[tid >> 6] = ssum;
    __syncthreads();
    ssum = reds[0] + reds[1] + reds[2] + reds[3];
    const float inv = 1.0f / ssum;

    #pragma unroll
    for (int j = 0; j < 4; ++j) {
        int idx = tid + j * 256;
        if (idx <= t) row[idx] = e[j] * inv;
    }
}

// ---------------------------------------------------------------------------
// K5: O[n,t,:] = sum_s P[n,t,s] V[n,s,:]  via bf16 MFMA (64t x 128d / block).
// A[m=t][k=s] from P (causal-masked on load), B[k=s][n=d] from V transposed.
// ---------------------------------------------------------------------------
__global__ __launch_bounds__(256, 4) void av_mfma(const float* __restrict__ P,
                                                  const float* __restrict__ V,
                                                  float* __restrict__ O) {
    const int n  = blockIdx.x;
    const int tt = 15 - blockIdx.y;      // big tiles first (load balance)

    __shared__ int Pt[64 * 16];          // [t][s-pair ^ swz]
    __shared__ int Vt[128 * 16];         // [d][s-pair ^ swz]

    const int tid = threadIdx.x;
    const int wv = tid >> 6, ln = tid & 63;
    const int frow = ln & 15, quad = ln >> 4;

    const float* Pn = P + ((size_t)n * T_DIM + (size_t)tt * 64) * S_DIM;
    const float* Vn = V + (size_t)n * S_DIM * D_HEAD;

    floatx4 acc[8] = {};
    const int nsteps = (tt + 1) * 2;

    for (int sb = 0; sb < nsteps; ++sb) {
        const int sbase = sb * 32;
        __syncthreads();
        // P: 64t x 32s fp32, mask s>t, pack
        #pragma unroll
        for (int rep = 0; rep < 2; ++rep) {
            int idx = tid + rep * 256;
            int row = idx >> 3;
            int c4  = (idx & 7) * 4;
            float4 p = *(const float4*)(Pn + (size_t)row * S_DIM + sbase + c4);
            int tg = tt * 64 + row, sg = sbase + c4;
            p.x = (sg + 0 <= tg) ? p.x : 0.0f;
            p.y = (sg + 1 <= tg) ? p.y : 0.0f;
            p.z = (sg + 2 <= tg) ? p.z : 0.0f;
            p.w = (sg + 3 <= tg) ? p.w : 0.0f;
            int2 v; v.x = pack_bf16(p.x, p.y); v.y = pack_bf16(p.z, p.w);
            int pi = c4 >> 1;
            *(int2*)&Pt[row * 16 + (pi ^ (4 * (row & 3)))] = v;
        }
        // V: 32s x 128d fp32 -> transposed bf16 pairs
        #pragma unroll
        for (int rep = 0; rep < 2; ++rep) {
            int idx = tid + rep * 256;                  // 512 tasks
            int d0 = (idx & 7) * 4 + (idx >> 7) * 32;   // 0..124 step 4
            int sp = (idx >> 3) & 15;                   // s-pair 0..15
            const float* va = Vn + (size_t)(sbase + 2 * sp) * D_HEAD + d0;
            float4 a = *(const float4*)va;
            float4 b = *(const float4*)(va + D_HEAD);
            int pk[4];
            pk[0] = pack_bf16(a.x, b.x); pk[1] = pack_bf16(a.y, b.y);
            pk[2] = pack_bf16(a.z, b.z); pk[3] = pack_bf16(a.w, b.w);
            #pragma unroll
            for (int i = 0; i < 4; ++i)
                Vt[(d0 + i) * 16 + (sp ^ (4 * ((d0 + i) & 3)))] = pk[i];
        }
        __syncthreads();

        const int swz = 4 * (frow & 3);
        const short8 af = *(const short8*)&Pt[(wv * 16 + frow) * 16 + ((quad * 4) ^ swz)];
        #pragma unroll
        for (int dc = 0; dc < 8; ++dc) {
            const short8 bf = *(const short8*)&Vt[(dc * 16 + frow) * 16 + ((quad * 4) ^ swz)];
            acc[dc] = __builtin_amdgcn_mfma_f32_16x16x32_bf16(af, bf, acc[dc], 0, 0, 0);
        }
    }

    const int tg = tt * 64 + wv * 16 + quad * 4;
    #pragma unroll
    for (int dc = 0; dc < 8; ++dc)
        #pragma unroll
        for (int r = 0; r < 4; ++r)
            O[((size_t)n * T_DIM + tg + r) * D_HEAD + dc * 16 + frow] = acc[dc][r];
}

// ---------------------------------------------------------------------------
extern "C" void kernel_launch(void* const* d_in, const int* in_sizes, int n_in,
                              void* d_out, int out_size, void* d_ws, size_t ws_size,
                              hipStream_t stream) {
    const float* Q    = (const float*)d_in[0];
    const float* K    = (const float*)d_in[1];
    const float* V    = (const float*)d_in[2];
    const float* sw_pre  = (const float*)d_in[4];
    const float* qw1_pre = (const float*)d_in[5];
    const float* qw2_pre = (const float*)d_in[6];
    const float* kw1_pre = (const float*)d_in[7];
    const float* kw2_pre = (const float*)d_in[8];
    const float* qdd_pre = (const float*)d_in[9];
    const float* kdd_pre = (const float*)d_in[10];
    const float* sw_post  = (const float*)d_in[11];
    const float* qw1_post = (const float*)d_in[12];
    const float* qw2_post = (const float*)d_in[13];
    const float* kw1_post = (const float*)d_in[14];
    const float* kw2_post = (const float*)d_in[15];
    const float* qdd_post = (const float*)d_in[16];
    const float* kdd_post = (const float*)d_in[17];

    float* L = (float*)d_ws;          // [N][T][S] fp32, 134 MB
    float* O = (float*)d_out;

    ushort* mats  = (ushort*)d_out;   // consumed before av overwrites d_out
    ushort* Cpre  = mats + 0 * 1024 * 1024;
    ushort* Kpre  = mats + 1 * 1024 * 1024;
    ushort* Cpost = mats + 2 * 1024 * 1024;
    ushort* Kpost = mats + 3 * 1024 * 1024;

    mat_kernel<<<1024, 256, 0, stream>>>(sw_pre,  qw1_pre,  qw2_pre,  qdd_pre,  1.0f, Cpre);
    mat_kernel<<<1024, 256, 0, stream>>>(nullptr, kw1_pre,  kw2_pre,  kdd_pre,  0.0f, Kpre);
    mat_kernel<<<1024, 256, 0, stream>>>(sw_post, qw1_post, qw2_post, qdd_post, 1.0f, Cpost);
    mat_kernel<<<1024, 256, 0, stream>>>(nullptr, kw1_post, kw2_post, kdd_post, 0.0f, Kpost);

    qk_mfma<<<dim3(16, 16, 32), 256, 0, stream>>>(Q, K, L);
    proj_mfma<<<dim3(64, 32), 256, 0, stream>>>(L, Cpre, Kpre);
    softmax_kernel<<<dim3(1024, 32), 256, 0, stream>>>(L);
    proj_mfma<<<dim3(64, 32), 256, 0, stream>>>(L, Cpost, Kpost);
    av_mfma<<<dim3(32, 16), 256, 0, stream>>>(L, V, O);
}